// Round 5
// baseline (211.407 us; speedup 1.0000x reference)
//
#include <hip/hip_runtime.h>
#include <stdint.h>

#define B_ 16
#define N_ 1025
#define D_ 512
#define H_ 8
#define HD 64
#define NP 1152           // padded N: 18*64 = 9*128
#define WM 36             // bitmask u32 words per row (36*32 = 1152 bits exactly)
#define M_ (B_*N_)        // 16400 (real rows)
#define MP (B_*NP)        // 18432 = 144*128 padded rows
#define NT 18             // KV tiles of 64

typedef unsigned short u16;
typedef __attribute__((ext_vector_type(8))) short bf16x8;
typedef __attribute__((ext_vector_type(8))) u16 u16x8;
typedef __attribute__((ext_vector_type(4))) float f32x4;

typedef __attribute__((address_space(1))) const uint32_t gld_t;
typedef __attribute__((address_space(3))) uint32_t lds_t;

__device__ __forceinline__ u16 f2bf(float f) {
  uint32_t u = __float_as_uint(f);
  u += 0x7FFFu + ((u >> 16) & 1u);   // RNE
  return (u16)(u >> 16);
}

__device__ __forceinline__ uint32_t cvtpk(float a, float b) {
  uint32_t r;
  asm("v_cvt_pk_bf16_f32 %0, %1, %2" : "=v"(r) : "v"(a), "v"(b));
  return r;
}

__device__ __forceinline__ void gload16(const void* g, void* l) {
  __builtin_amdgcn_global_load_lds((gld_t*)g, (lds_t*)l, 16, 0, 0);
}

// ---------------- K0: pack attn_mask into bitmask [NP][WM] u32 ----------------
__global__ void k_bitmask(const float* __restrict__ mask, uint32_t* __restrict__ bm) {
  int r = blockIdx.x;
  int wave = threadIdx.x >> 6, lane = threadIdx.x & 63;
  for (int chunk = wave; chunk < NT; chunk += 4) {
    int kv = chunk * 64 + lane;
    bool pred = (r < N_) && (kv < N_) && (mask[(size_t)r * N_ + kv] != 0.0f);
    unsigned long long bal = __ballot(pred);
    if (lane == 0) {
      bm[r * WM + chunk * 2]     = (uint32_t)bal;
      bm[r * WM + chunk * 2 + 1] = (uint32_t)(bal >> 32);
    }
  }
}

// ---------------- K1: convert+transpose weights to bf16 ----------------
__global__ void k_wconv(const float* __restrict__ wqkv, const float* __restrict__ wproj,
                        u16* __restrict__ wtq, u16* __restrict__ wtp) {
  int idx = blockIdx.x * 256 + threadIdx.x;
  if (idx < 3 * D_ * D_) {
    int k = idx / (3 * D_), c = idx % (3 * D_);
    wtq[c * D_ + k] = f2bf(wqkv[idx]);
  }
  if (idx < D_ * D_) {
    int k = idx >> 9, c = idx & 511;
    wtp[c * D_ + k] = f2bf(wproj[idx]);
  }
}

// ---------------- K2: x -> bf16, padded [B][NP][D], padded rows zeroed ----------------
__global__ void k_xconv(const float* __restrict__ x, u16* __restrict__ xb) {
  int i = blockIdx.x * 256 + threadIdx.x;
  int idx = i * 8;
  int pr = idx >> 9;
  int col = idx & 511;
  int b = pr / NP, n = pr - b * NP;
  u16x8 o;
  if (n < N_) {
    const float* src = x + ((size_t)b * N_ + n) * D_ + col;
    float4 v0 = *reinterpret_cast<const float4*>(src);
    float4 v1 = *reinterpret_cast<const float4*>(src + 4);
    o[0] = f2bf(v0.x); o[1] = f2bf(v0.y); o[2] = f2bf(v0.z); o[3] = f2bf(v0.w);
    o[4] = f2bf(v1.x); o[5] = f2bf(v1.y); o[6] = f2bf(v1.z); o[7] = f2bf(v1.w);
  } else {
    o = (u16x8){0,0,0,0,0,0,0,0};
  }
  *reinterpret_cast<u16x8*>(xb + idx) = o;
}

// ================= 128x128 tiled GEMM, 2-phase dbuf =================

// ---------------- K3: QKV GEMM -> Q (scaled by 0.125*log2e), K, V ----------------
__global__ __launch_bounds__(256) void k_qkv(const u16* __restrict__ xb, const u16* __restrict__ wtq,
                                             u16* __restrict__ Q, u16* __restrict__ K,
                                             u16* __restrict__ V) {
  __shared__ u16 sA[2][128 * 64];
  __shared__ u16 sB[2][128 * 64];
  const int m0 = blockIdx.y * 128;
  const int n0 = blockIdx.x * 128;
  const int t = threadIdx.x;
  const int wave = t >> 6, lane = t & 63;
  const int wm = wave >> 1, wn = wave & 1;
  const int lq = lane & 15, lg = lane >> 4;

  const int srow = lane >> 3;
  const int schunk = (lane & 7) ^ srow;

  f32x4 acc[4][4] = {};

#define QSTAGE(buf, k0_)                                                          \
  {                                                                               \
    _Pragma("unroll")                                                             \
    for (int p = 0; p < 4; ++p) {                                                 \
      int row = p * 32 + wave * 8 + srow;                                         \
      gload16(xb + (size_t)(m0 + row) * 512 + (k0_) + schunk * 8,                 \
              &sA[buf][p * 2048 + wave * 512 + lane * 8]);                        \
      gload16(wtq + (size_t)(n0 + row) * 512 + (k0_) + schunk * 8,                \
              &sB[buf][p * 2048 + wave * 512 + lane * 8]);                        \
    }                                                                             \
  }

  QSTAGE(0, 0);
  __syncthreads();
  int cur = 0;
  for (int k0 = 0; k0 < 512; k0 += 64) {
    if (k0 < 448) QSTAGE(cur ^ 1, k0 + 64);
#pragma unroll
    for (int kk = 0; kk < 2; ++kk) {
      bf16x8 af[4], bff[4];
      const int pc = (kk * 4 + lg) ^ (lq & 7);
#pragma unroll
      for (int f = 0; f < 4; ++f) {
        af[f]  = *reinterpret_cast<const bf16x8*>(&sA[cur][(wm * 64 + f * 16 + lq) * 64 + pc * 8]);
        bff[f] = *reinterpret_cast<const bf16x8*>(&sB[cur][(wn * 64 + f * 16 + lq) * 64 + pc * 8]);
      }
#pragma unroll
      for (int i = 0; i < 4; ++i)
#pragma unroll
        for (int j = 0; j < 4; ++j)
          acc[i][j] = __builtin_amdgcn_mfma_f32_16x16x32_bf16(af[i], bff[j], acc[i][j], 0, 0, 0);
    }
    __syncthreads();
    cur ^= 1;
  }
#undef QSTAGE

#pragma unroll
  for (int j = 0; j < 4; ++j) {
    int c = n0 + wn * 64 + j * 16 + lq;
    int which = c >> 9, h = (c >> 6) & 7, d = c & 63;
#pragma unroll
    for (int i = 0; i < 4; ++i) {
      int mbase = m0 + wm * 64 + i * 16 + lg * 4;
#pragma unroll
      for (int r = 0; r < 4; ++r) {
        int m = mbase + r;
        int b = m / NP, n = m - b * NP;
        int bh = b * H_ + h;
        float v = acc[i][j][r];
        if (which == 0)      Q[((size_t)bh * NP + n) * HD + d] = f2bf(v * 0.18033688f); // 0.125*log2(e)
        else if (which == 1) K[((size_t)bh * NP + n) * HD + d] = f2bf(v);
        else                 V[((size_t)bh * NP + n) * HD + d] = f2bf(v);  // coalesced [n][d]
      }
    }
  }
}

// ---------------- K3b: transpose V [bh][n][d] -> Vt [bh][d][n] ----------------
__global__ __launch_bounds__(256) void k_vt(const u16* __restrict__ V, u16* __restrict__ Vt) {
  __shared__ u16 s[64][72];
  int n0 = blockIdx.x * 64, bh = blockIdx.y;
  int t = threadIdx.x;
  int r = t >> 3, c = t & 7;
  const u16* src = V + ((size_t)bh * NP + n0) * HD;
  *reinterpret_cast<u16x8*>(&s[r][c * 8])      = *reinterpret_cast<const u16x8*>(src + r * HD + c * 8);
  *reinterpret_cast<u16x8*>(&s[r + 32][c * 8]) = *reinterpret_cast<const u16x8*>(src + (r + 32) * HD + c * 8);
  __syncthreads();
  int d = t >> 2, cc0 = t & 3;
  u16* dst = Vt + ((size_t)bh * HD + d) * NP + n0;
#pragma unroll
  for (int rep = 0; rep < 2; ++rep) {
    int cc = cc0 + rep * 4;
    u16x8 o;
#pragma unroll
    for (int jj = 0; jj < 8; ++jj) o[jj] = s[cc * 8 + jj][d];
    *reinterpret_cast<u16x8*>(dst + cc * 8) = o;
  }
}

// ---------------- K4: flash attention, 8 waves, QBLK=128, counted-vmcnt pipeline ----------------
// grid: 9 q-tiles * 128 bh = 1152 blocks, XCD-swizzled.
__global__ __launch_bounds__(512) void k_attn(const u16* __restrict__ Q, const u16* __restrict__ K,
                                              const u16* __restrict__ Vt, const uint32_t* __restrict__ bm,
                                              u16* __restrict__ O) {
  __shared__ u16 sK[2][64 * 64];
  __shared__ u16 sV[2][64 * 64];
  __shared__ u16 sP[8][16 * 64];

  int bid = blockIdx.x;
  int wg = (bid & 7) * (9 * 128 / 8) + (bid >> 3);   // XCD swizzle (1152 % 8 == 0)
  int bh = wg / 9, qt = wg - bh * 9;
  int b = bh >> 3, h = bh & 7;
  int t = threadIdx.x;
  int w = t >> 6, lane = t & 63;
  int lq = lane & 15, lg = lane >> 4;
  int qbase = qt * 128 + w * 16;
  int qrow = qbase + lq;
  const u16* Qp = Q + ((size_t)bh * NP + qbase) * HD;
  const u16* Kp = K + (size_t)bh * NP * HD;
  const u16* Vp = Vt + (size_t)bh * HD * NP;
  const uint2* bmrow2 = reinterpret_cast<const uint2*>(bm + (size_t)qrow * WM);

  bf16x8 qf0 = *reinterpret_cast<const bf16x8*>(Qp + lq * HD + lg * 8);
  bf16x8 qf1 = *reinterpret_cast<const bf16x8*>(Qp + lq * HD + 32 + lg * 8);

  // staging: K tile 64x64 = 512 chunks of 16B; thread t stages chunk t of K and of V
  const int srow = t >> 3, sch = (t & 7) ^ (srow & 7);

  f32x4 oacc[4] = {};
  float lpart = 0.f;

#define STAGE(buf, kv0_)                                                        \
  {                                                                             \
    gload16(Kp + (size_t)((kv0_) + srow) * HD + sch * 8, &sK[buf][t * 8]);      \
    gload16(Vp + (size_t)srow * NP + (kv0_) + sch * 8,   &sV[buf][t * 8]);      \
  }

#define COMPUTE(buf, mx, my)                                                     \
  {                                                                              \
    f32x4 s[4] = {};                                                             \
    __builtin_amdgcn_s_setprio(1);                                               \
    _Pragma("unroll")                                                            \
    for (int kk = 0; kk < 2; ++kk) {                                             \
      bf16x8 qf = kk ? qf1 : qf0;                                                \
      int pc = (kk * 4 + lg) ^ (lq & 7);                                         \
      _Pragma("unroll")                                                          \
      for (int f = 0; f < 4; ++f) {                                              \
        bf16x8 kf = *reinterpret_cast<const bf16x8*>(&sK[buf][(f * 16 + lq) * 64 + pc * 8]); \
        s[f] = __builtin_amdgcn_mfma_f32_16x16x32_bf16(kf, qf, s[f], 0, 0, 0);   \
      }                                                                          \
    }                                                                            \
    __builtin_amdgcn_s_setprio(0);                                               \
    uint32_t u0 = (mx) >> (4 * lg);                                              \
    uint32_t u1 = (my) >> (4 * lg);                                              \
    _Pragma("unroll")                                                            \
    for (int f = 0; f < 4; ++f) {                                                \
      uint32_t uu = (f & 2) ? u1 : u0;                                           \
      int sh = (f & 1) * 16;                                                     \
      _Pragma("unroll")                                                          \
      for (int r = 0; r < 4; ++r) {                                              \
        float pv = (uu & (1u << (sh + r))) ? exp2f(s[f][r]) : 0.f;               \
        s[f][r] = pv;                                                            \
        lpart += pv;                                                             \
      }                                                                          \
    }                                                                            \
    _Pragma("unroll")                                                            \
    for (int f = 0; f < 4; ++f) {                                                \
      uint2 pw;                                                                  \
      pw.x = cvtpk(s[f][0], s[f][1]);                                            \
      pw.y = cvtpk(s[f][2], s[f][3]);                                            \
      int pch = (2 * f + (lg >> 1)) ^ (lq & 7);                                  \
      *reinterpret_cast<uint2*>(&sP[w][lq * 64 + pch * 8 + (lg & 1) * 4]) = pw;  \
    }                                                                            \
    __builtin_amdgcn_s_setprio(1);                                               \
    _Pragma("unroll")                                                            \
    for (int kk = 0; kk < 2; ++kk) {                                             \
      int pc = (kk * 4 + lg) ^ (lq & 7);                                         \
      bf16x8 pf = *reinterpret_cast<const bf16x8*>(&sP[w][lq * 64 + pc * 8]);    \
      _Pragma("unroll")                                                          \
      for (int j = 0; j < 4; ++j) {                                              \
        bf16x8 vf = *reinterpret_cast<const bf16x8*>(&sV[buf][(j * 16 + lq) * 64 + pc * 8]); \
        oacc[j] = __builtin_amdgcn_mfma_f32_16x16x32_bf16(pf, vf, oacc[j], 0, 0, 0); \
      }                                                                          \
    }                                                                            \
    __builtin_amdgcn_s_setprio(0);                                               \
  }

  STAGE(0, 0);
  uint2 mw_cur = bmrow2[0];
  int buf = 0;
  for (int ti = 0; ti < NT - 1; ++ti) {
    STAGE(buf ^ 1, (ti + 1) * 64);
    uint2 mw_nxt = bmrow2[ti + 1];
    // tile-ti loads (older) complete; 3 newest (2 stage + 1 mask) stay in flight
    asm volatile("s_waitcnt vmcnt(3)" ::: "memory");
    __builtin_amdgcn_s_barrier();
    COMPUTE(buf, mw_cur.x, mw_cur.y);
    __builtin_amdgcn_s_barrier();   // all waves done reading buf before it's restaged
    mw_cur = mw_nxt;
    buf ^= 1;
  }
  asm volatile("s_waitcnt vmcnt(0)" ::: "memory");
  __builtin_amdgcn_s_barrier();
  COMPUTE(buf, mw_cur.x, mw_cur.y);
#undef STAGE
#undef COMPUTE

  // deferred l reduction: combine the 4 lanes holding row lq
  lpart += __shfl_xor(lpart, 16);
  lpart += __shfl_xor(lpart, 32);

#pragma unroll
  for (int r = 0; r < 4; ++r) {
    int n = qbase + 4 * lg + r;
    float lr = __shfl(lpart, 4 * lg + r);
    float linv = (lr > 0.f) ? 1.f / lr : 0.f;
    size_t mrow = (size_t)b * NP + n;
#pragma unroll
    for (int j = 0; j < 4; ++j)
      O[mrow * D_ + h * HD + j * 16 + lq] = f2bf(oacc[j][r] * linv);
  }
}

// ---------------- K5: proj GEMM + bias -> fp32 (padded M), 2-phase dbuf ----------------
__global__ __launch_bounds__(256) void k_proj(const u16* __restrict__ ob, const u16* __restrict__ wtp,
                                              const float* __restrict__ bias, float* __restrict__ oproj) {
  __shared__ u16 sA[2][128 * 64];
  __shared__ u16 sB[2][128 * 64];
  const int m0 = blockIdx.y * 128;
  const int n0 = blockIdx.x * 128;
  const int t = threadIdx.x;
  const int wave = t >> 6, lane = t & 63;
  const int wm = wave >> 1, wn = wave & 1;
  const int lq = lane & 15, lg = lane >> 4;

  const int srow = lane >> 3;
  const int schunk = (lane & 7) ^ srow;

  f32x4 acc[4][4] = {};

#define PSTAGE(buf, k0_)                                                          \
  {                                                                               \
    _Pragma("unroll")                                                             \
    for (int p = 0; p < 4; ++p) {                                                 \
      int row = p * 32 + wave * 8 + srow;                                         \
      gload16(ob + (size_t)(m0 + row) * 512 + (k0_) + schunk * 8,                 \
              &sA[buf][p * 2048 + wave * 512 + lane * 8]);                        \
      gload16(wtp + (size_t)(n0 + row) * 512 + (k0_) + schunk * 8,                \
              &sB[buf][p * 2048 + wave * 512 + lane * 8]);                        \
    }                                                                             \
  }

  PSTAGE(0, 0);
  __syncthreads();
  int cur = 0;
  for (int k0 = 0; k0 < 512; k0 += 64) {
    if (k0 < 448) PSTAGE(cur ^ 1, k0 + 64);
#pragma unroll
    for (int kk = 0; kk < 2; ++kk) {
      bf16x8 af[4], bff[4];
      const int pc = (kk * 4 + lg) ^ (lq & 7);
#pragma unroll
      for (int f = 0; f < 4; ++f) {
        af[f]  = *reinterpret_cast<const bf16x8*>(&sA[cur][(wm * 64 + f * 16 + lq) * 64 + pc * 8]);
        bff[f] = *reinterpret_cast<const bf16x8*>(&sB[cur][(wn * 64 + f * 16 + lq) * 64 + pc * 8]);
      }
#pragma unroll
      for (int i = 0; i < 4; ++i)
#pragma unroll
        for (int j = 0; j < 4; ++j)
          acc[i][j] = __builtin_amdgcn_mfma_f32_16x16x32_bf16(af[i], bff[j], acc[i][j], 0, 0, 0);
    }
    __syncthreads();
    cur ^= 1;
  }
#undef PSTAGE

#pragma unroll
  for (int j = 0; j < 4; ++j) {
    int c = n0 + wn * 64 + j * 16 + lq;
    float bv = bias[c];
#pragma unroll
    for (int i = 0; i < 4; ++i) {
      int mbase = m0 + wm * 64 + i * 16 + lg * 4;
#pragma unroll
      for (int r = 0; r < 4; ++r) {
        int m = mbase + r;
        oproj[(size_t)m * D_ + c] = acc[i][j][r] + bv;
      }
    }
  }
}

// ---------------- K6: LN + residual (reads padded, writes real) ----------------
__global__ __launch_bounds__(256) void k_ln(const float* __restrict__ op, const float* __restrict__ gamma,
                                            const float* __restrict__ beta, float* __restrict__ out) {
  int row = blockIdx.x;
  int b = row / N_, n = row - b * N_;
  int t = threadIdx.x;
  const float* r = op + ((size_t)b * NP + n) * D_;
  float v0 = r[t], v1 = r[t + 256];
  float s = v0 + v1, sq = v0 * v0 + v1 * v1;
#pragma unroll
  for (int off = 1; off < 64; off <<= 1) { s += __shfl_xor(s, off); sq += __shfl_xor(sq, off); }
  __shared__ float ls[4], lsq[4];
  int wave = t >> 6, lane = t & 63;
  if (lane == 0) { ls[wave] = s; lsq[wave] = sq; }
  __syncthreads();
  float S = ls[0] + ls[1] + ls[2] + ls[3];
  float SQ = lsq[0] + lsq[1] + lsq[2] + lsq[3];
  float mu = S * (1.f / 512.f);
  float var = SQ * (1.f / 512.f) - mu * mu;
  float rinv = rsqrtf(var + 1e-5f);
  float g0 = gamma[t], g1 = gamma[t + 256], b0 = beta[t], b1 = beta[t + 256];
  out[(size_t)row * D_ + t]       = v0 + (v0 - mu) * rinv * g0 + b0;
  out[(size_t)row * D_ + t + 256] = v1 + (v1 - mu) * rinv * g1 + b1;
}

extern "C" void kernel_launch(void* const* d_in, const int* in_sizes, int n_in,
                              void* d_out, int out_size, void* d_ws, size_t ws_size,
                              hipStream_t stream) {
  const float* x     = (const float*)d_in[0];
  const float* wqkv  = (const float*)d_in[1];
  const float* wproj = (const float*)d_in[2];
  const float* bproj = (const float*)d_in[3];
  const float* gamma = (const float*)d_in[4];
  const float* beta  = (const float*)d_in[5];
  const float* mask  = (const float*)d_in[6];
  float* out = (float*)d_out;

  char* ws = (char*)d_ws;
  size_t off = 0;
  auto alloc = [&](size_t bytes) {
    void* p = ws + off;
    off = (off + bytes + 255) & ~(size_t)255;
    return p;
  };
  uint32_t* bmask = (uint32_t*)alloc((size_t)NP * WM * 4);
  u16* wtq  = (u16*)alloc((size_t)3 * D_ * D_ * 2);
  u16* wtp  = (u16*)alloc((size_t)D_ * D_ * 2);
  u16* xb   = (u16*)alloc((size_t)MP * D_ * 2);
  u16* Qb   = (u16*)alloc((size_t)128 * NP * HD * 2);
  u16* Kb   = (u16*)alloc((size_t)128 * NP * HD * 2);
  u16* Vb   = (u16*)alloc((size_t)128 * NP * HD * 2);
  u16* Vtb  = (u16*)alloc((size_t)128 * HD * NP * 2);
  u16* Ob   = (u16*)alloc((size_t)MP * D_ * 2);
  float* oproj = (float*)alloc((size_t)MP * D_ * 4);

  k_bitmask<<<dim3(NP), dim3(256), 0, stream>>>(mask, bmask);
  k_wconv<<<dim3(3072), dim3(256), 0, stream>>>(wqkv, wproj, wtq, wtp);
  k_xconv<<<dim3(MP * D_ / (256 * 8)), dim3(256), 0, stream>>>(x, xb);
  k_qkv<<<dim3(12, MP / 128), dim3(256), 0, stream>>>(xb, wtq, Qb, Kb, Vb);
  k_vt<<<dim3(NP / 64, 128), dim3(256), 0, stream>>>(Vb, Vtb);
  k_attn<<<dim3(9 * 128), dim3(512), 0, stream>>>(Qb, Kb, Vtb, bmask, Ob);
  k_proj<<<dim3(4, MP / 128), dim3(256), 0, stream>>>(Ob, wtp, bproj, oproj);
  k_ln<<<dim3(M_), dim3(256), 0, stream>>>(oproj, gamma, beta, out);
}

// Round 6
// 191.597 us; speedup vs baseline: 1.1034x; 1.1034x over previous
//
#include <hip/hip_runtime.h>
#include <stdint.h>

#define B_ 16
#define N_ 1025
#define D_ 512
#define H_ 8
#define HD 64
#define NP 1152           // padded N: 9*128 (q side)
#define WM 36             // bitmask u32 words per row
#define M_ (B_*N_)        // 16400 (real rows)
#define MP (B_*NP)        // 18432 = 144*128 padded rows
#define NTKV 17           // KV tiles of 64 actually processed (17*64=1088 >= 1025)
#define NQG 72            // q-groups of 16 (NP/16)

typedef unsigned short u16;
typedef __attribute__((ext_vector_type(8))) short bf16x8;
typedef __attribute__((ext_vector_type(4))) u16 u16x4;
typedef __attribute__((ext_vector_type(8))) u16 u16x8;
typedef __attribute__((ext_vector_type(4))) float f32x4;

typedef __attribute__((address_space(1))) const uint32_t gld_t;
typedef __attribute__((address_space(3))) uint32_t lds_t;

__device__ __forceinline__ u16 f2bf(float f) {
  uint32_t u = __float_as_uint(f);
  u += 0x7FFFu + ((u >> 16) & 1u);   // RNE
  return (u16)(u >> 16);
}

__device__ __forceinline__ uint32_t cvtpk(float a, float b) {
  uint32_t r;
  asm("v_cvt_pk_bf16_f32 %0, %1, %2" : "=v"(r) : "v"(a), "v"(b));
  return r;
}

__device__ __forceinline__ float exp2a(float x) {   // bare v_exp_f32 (no OCML fixup)
  float r;
  asm("v_exp_f32 %0, %1\n\ts_nop 0" : "=v"(r) : "v"(x));
  return r;
}

__device__ __forceinline__ void gload16(const void* g, void* l) {
  __builtin_amdgcn_global_load_lds((gld_t*)g, (lds_t*)l, 16, 0, 0);
}

// ---------------- K0: pack attn_mask into bitmask [NP][WM] u32 ----------------
__global__ void k_bitmask(const float* __restrict__ mask, uint32_t* __restrict__ bm) {
  int r = blockIdx.x;
  int wave = threadIdx.x >> 6, lane = threadIdx.x & 63;
  for (int chunk = wave; chunk < 18; chunk += 4) {
    int kv = chunk * 64 + lane;
    bool pred = (r < N_) && (kv < N_) && (mask[(size_t)r * N_ + kv] != 0.0f);
    unsigned long long bal = __ballot(pred);
    if (lane == 0) {
      bm[r * WM + chunk * 2]     = (uint32_t)bal;
      bm[r * WM + chunk * 2 + 1] = (uint32_t)(bal >> 32);
    }
  }
}

// ---------------- K0b: additive mask in MFMA C-fragment layout ----------------
// am[qg][ti][lane][f*4+r] : 0.0 if mask bit set else -30000 (exp2 -> exactly 0)
__global__ __launch_bounds__(64) void k_amask(const uint32_t* __restrict__ bm, float* __restrict__ am) {
  int qg = blockIdx.x, ti = blockIdx.y;
  int lane = threadIdx.x;
  int lq = lane & 15, lg = lane >> 4;
  int q = qg * 16 + lq;
  size_t base = ((size_t)(qg * NTKV + ti) * 64 + lane) * 16;
#pragma unroll
  for (int f = 0; f < 4; ++f) {
    f32x4 o;
#pragma unroll
    for (int r = 0; r < 4; ++r) {
      int kv = ti * 64 + f * 16 + 4 * lg + r;
      uint32_t bit = (bm[q * WM + (kv >> 5)] >> (kv & 31)) & 1u;
      o[r] = bit ? 0.f : -30000.f;
    }
    *reinterpret_cast<f32x4*>(am + base + f * 4) = o;
  }
}

// ---------------- K1: convert+transpose weights to bf16 ----------------
__global__ void k_wconv(const float* __restrict__ wqkv, const float* __restrict__ wproj,
                        u16* __restrict__ wtq, u16* __restrict__ wtp) {
  int idx = blockIdx.x * 256 + threadIdx.x;
  if (idx < 3 * D_ * D_) {
    int k = idx / (3 * D_), c = idx % (3 * D_);
    wtq[c * D_ + k] = f2bf(wqkv[idx]);
  }
  if (idx < D_ * D_) {
    int k = idx >> 9, c = idx & 511;
    wtp[c * D_ + k] = f2bf(wproj[idx]);
  }
}

// ---------------- K2: x -> bf16, padded [B][NP][D], padded rows zeroed ----------------
__global__ void k_xconv(const float* __restrict__ x, u16* __restrict__ xb) {
  int i = blockIdx.x * 256 + threadIdx.x;
  int idx = i * 8;
  int pr = idx >> 9;
  int col = idx & 511;
  int b = pr / NP, n = pr - b * NP;
  u16x8 o;
  if (n < N_) {
    const float* src = x + ((size_t)b * N_ + n) * D_ + col;
    float4 v0 = *reinterpret_cast<const float4*>(src);
    float4 v1 = *reinterpret_cast<const float4*>(src + 4);
    o[0] = f2bf(v0.x); o[1] = f2bf(v0.y); o[2] = f2bf(v0.z); o[3] = f2bf(v0.w);
    o[4] = f2bf(v1.x); o[5] = f2bf(v1.y); o[6] = f2bf(v1.z); o[7] = f2bf(v1.w);
  } else {
    o = (u16x8){0,0,0,0,0,0,0,0};
  }
  *reinterpret_cast<u16x8*>(xb + idx) = o;
}

// ---------------- K3: QKV GEMM -> Q (scaled by 0.125*log2e), K, Vt (fused transpose) ----------------
__global__ __launch_bounds__(256) void k_qkv(const u16* __restrict__ xb, const u16* __restrict__ wtq,
                                             u16* __restrict__ Q, u16* __restrict__ K,
                                             u16* __restrict__ Vt) {
  __shared__ u16 sA[2][128 * 64];
  __shared__ u16 sB[2][128 * 64];
  const int m0 = blockIdx.y * 128;
  const int n0 = blockIdx.x * 128;
  const int t = threadIdx.x;
  const int wave = t >> 6, lane = t & 63;
  const int wm = wave >> 1, wn = wave & 1;
  const int lq = lane & 15, lg = lane >> 4;

  const int srow = lane >> 3;
  const int schunk = (lane & 7) ^ srow;

  f32x4 acc[4][4] = {};

#define QSTAGE(buf, k0_)                                                          \
  {                                                                               \
    _Pragma("unroll")                                                             \
    for (int p = 0; p < 4; ++p) {                                                 \
      int row = p * 32 + wave * 8 + srow;                                         \
      gload16(xb + (size_t)(m0 + row) * 512 + (k0_) + schunk * 8,                 \
              &sA[buf][p * 2048 + wave * 512 + lane * 8]);                        \
      gload16(wtq + (size_t)(n0 + row) * 512 + (k0_) + schunk * 8,                \
              &sB[buf][p * 2048 + wave * 512 + lane * 8]);                        \
    }                                                                             \
  }

  QSTAGE(0, 0);
  __syncthreads();
  int cur = 0;
  for (int k0 = 0; k0 < 512; k0 += 64) {
    if (k0 < 448) QSTAGE(cur ^ 1, k0 + 64);
#pragma unroll
    for (int kk = 0; kk < 2; ++kk) {
      bf16x8 af[4], bff[4];
      const int pc = (kk * 4 + lg) ^ (lq & 7);
#pragma unroll
      for (int f = 0; f < 4; ++f) {
        af[f]  = *reinterpret_cast<const bf16x8*>(&sA[cur][(wm * 64 + f * 16 + lq) * 64 + pc * 8]);
        bff[f] = *reinterpret_cast<const bf16x8*>(&sB[cur][(wn * 64 + f * 16 + lq) * 64 + pc * 8]);
      }
#pragma unroll
      for (int i = 0; i < 4; ++i)
#pragma unroll
        for (int j = 0; j < 4; ++j)
          acc[i][j] = __builtin_amdgcn_mfma_f32_16x16x32_bf16(af[i], bff[j], acc[i][j], 0, 0, 0);
    }
    __syncthreads();
    cur ^= 1;
  }
#undef QSTAGE

  if (n0 >= 1024) {
    // ---- V block: transpose 128(m) x 128(c) through XOR-swizzled LDS, write Vt coalesced ----
    u16* T = (u16*)&sA[0][0];          // 128 x 128 u16 = 32 KB
#pragma unroll
    for (int j = 0; j < 4; ++j) {
      int c = wn * 64 + j * 16 + lq;                 // local col (0..127), c&15 == lq
#pragma unroll
      for (int i = 0; i < 4; ++i) {
        int mb = wm * 64 + i * 16 + lg * 4;          // local row base (step 4)
        u16x4 pw;
#pragma unroll
        for (int r = 0; r < 4; ++r) pw[r] = f2bf(acc[i][j][r]);
        *reinterpret_cast<u16x4*>(&T[c * 128 + ((((mb >> 3) ^ lq) << 3) | (mb & 7))]) = pw;
      }
    }
    __syncthreads();
    int c = t & 127;
    int ch0 = (t >> 7) << 3;
    int cg = n0 + c - 1024;                          // 0..511 V column
    int h = cg >> 6, d = cg & 63;
    int bb = m0 / NP;
    int nb = m0 - bb * NP;
    u16* dst = Vt + (((size_t)(bb * H_ + h) * HD + d) * NP + nb);
#pragma unroll
    for (int rep = 0; rep < 8; ++rep) {
      int chunk = ch0 + rep;
      u16x8 vv = *reinterpret_cast<const u16x8*>(&T[c * 128 + ((chunk ^ (c & 15)) << 3)]);
      *reinterpret_cast<u16x8*>(&dst[chunk * 8]) = vv;
    }
  } else {
    // ---- Q / K blocks: direct stores ----
#pragma unroll
    for (int j = 0; j < 4; ++j) {
      int c = n0 + wn * 64 + j * 16 + lq;
      int which = c >> 9, h = (c >> 6) & 7, d = c & 63;
#pragma unroll
      for (int i = 0; i < 4; ++i) {
        int mbase = m0 + wm * 64 + i * 16 + lg * 4;
#pragma unroll
        for (int r = 0; r < 4; ++r) {
          int m = mbase + r;
          int b = m / NP, n = m - b * NP;
          int bh = b * H_ + h;
          float v = acc[i][j][r];
          if (which == 0) Q[((size_t)bh * NP + n) * HD + d] = f2bf(v * 0.18033688f); // 0.125*log2(e)
          else            K[((size_t)bh * NP + n) * HD + d] = f2bf(v);
        }
      }
    }
  }
}

// ---------------- K4: flash attention, 8 waves, QBLK=128, counted-vmcnt, amask C-init ----------------
__global__ __launch_bounds__(512) void k_attn(const u16* __restrict__ Q, const u16* __restrict__ K,
                                              const u16* __restrict__ Vt, const float* __restrict__ am,
                                              u16* __restrict__ O) {
  __shared__ u16 sK[2][64 * 64];
  __shared__ u16 sV[2][64 * 64];
  __shared__ u16 sP[8][16 * 64];

  int bid = blockIdx.x;
  int wg = (bid & 7) * (9 * 128 / 8) + (bid >> 3);   // XCD swizzle (1152 % 8 == 0)
  int bh = wg / 9, qt = wg - bh * 9;
  int b = bh >> 3, h = bh & 7;
  int t = threadIdx.x;
  int w = t >> 6, lane = t & 63;
  int lq = lane & 15, lg = lane >> 4;
  int qbase = qt * 128 + w * 16;
  int qg = qt * 8 + w;
  const u16* Qp = Q + ((size_t)bh * NP + qbase) * HD;
  const u16* Kp = K + (size_t)bh * NP * HD;
  const u16* Vp = Vt + (size_t)bh * HD * NP;
  const float* amp = am + ((size_t)qg * NTKV * 64 + lane) * 16;

  bf16x8 qf0 = *reinterpret_cast<const bf16x8*>(Qp + lq * HD + lg * 8);
  bf16x8 qf1 = *reinterpret_cast<const bf16x8*>(Qp + lq * HD + 32 + lg * 8);

  const int srow = t >> 3, sch = (t & 7) ^ (srow & 7);

  f32x4 oacc[4] = {};
  float lpart = 0.f;

#define STAGE(buf, kv0_)                                                        \
  {                                                                             \
    gload16(Kp + (size_t)((kv0_) + srow) * HD + sch * 8, &sK[buf][t * 8]);      \
    gload16(Vp + (size_t)srow * NP + (kv0_) + sch * 8,   &sV[buf][t * 8]);      \
  }

#define AML(an, ti_)                                                            \
  {                                                                             \
    const f32x4* ap = reinterpret_cast<const f32x4*>(amp + (size_t)(ti_) * 64 * 16); \
    an[0] = ap[0]; an[1] = ap[1]; an[2] = ap[2]; an[3] = ap[3];                 \
  }

#define COMPUTE(buf, ac)                                                         \
  {                                                                              \
    f32x4 s[4] = {ac[0], ac[1], ac[2], ac[3]};   /* C-init = additive mask */    \
    __builtin_amdgcn_s_setprio(1);                                               \
    _Pragma("unroll")                                                            \
    for (int kk = 0; kk < 2; ++kk) {                                             \
      bf16x8 qf = kk ? qf1 : qf0;                                                \
      int pc = (kk * 4 + lg) ^ (lq & 7);                                         \
      _Pragma("unroll")                                                          \
      for (int f = 0; f < 4; ++f) {                                              \
        bf16x8 kf = *reinterpret_cast<const bf16x8*>(&sK[buf][(f * 16 + lq) * 64 + pc * 8]); \
        s[f] = __builtin_amdgcn_mfma_f32_16x16x32_bf16(kf, qf, s[f], 0, 0, 0);   \
      }                                                                          \
    }                                                                            \
    __builtin_amdgcn_s_setprio(0);                                               \
    _Pragma("unroll")                                                            \
    for (int f = 0; f < 4; ++f) {                                                \
      _Pragma("unroll")                                                          \
      for (int r = 0; r < 4; ++r) {                                              \
        float pv = exp2a(s[f][r]);                                               \
        s[f][r] = pv;                                                            \
        lpart += pv;                                                             \
      }                                                                          \
    }                                                                            \
    _Pragma("unroll")                                                            \
    for (int f = 0; f < 4; ++f) {                                                \
      uint2 pw;                                                                  \
      pw.x = cvtpk(s[f][0], s[f][1]);                                            \
      pw.y = cvtpk(s[f][2], s[f][3]);                                            \
      int pch = (2 * f + (lg >> 1)) ^ (lq & 7);                                  \
      *reinterpret_cast<uint2*>(&sP[w][lq * 64 + pch * 8 + (lg & 1) * 4]) = pw;  \
    }                                                                            \
    __builtin_amdgcn_s_setprio(1);                                               \
    _Pragma("unroll")                                                            \
    for (int kk = 0; kk < 2; ++kk) {                                             \
      int pc = (kk * 4 + lg) ^ (lq & 7);                                         \
      bf16x8 pf = *reinterpret_cast<const bf16x8*>(&sP[w][lq * 64 + pc * 8]);    \
      _Pragma("unroll")                                                          \
      for (int j = 0; j < 4; ++j) {                                              \
        bf16x8 vf = *reinterpret_cast<const bf16x8*>(&sV[buf][(j * 16 + lq) * 64 + pc * 8]); \
        oacc[j] = __builtin_amdgcn_mfma_f32_16x16x32_bf16(pf, vf, oacc[j], 0, 0, 0); \
      }                                                                          \
    }                                                                            \
    __builtin_amdgcn_s_setprio(0);                                               \
  }

// pipelined step: stage tile ti+1 (2 loads) + amask ti+1 (4 loads); wait for tile-ti's 6
#define STEP(bufb, ac, an, ti_)                                                  \
  {                                                                              \
    STAGE((bufb) ^ 1, ((ti_) + 1) * 64);                                         \
    AML(an, (ti_) + 1);                                                          \
    asm volatile("s_waitcnt vmcnt(6)" ::: "memory");                             \
    __builtin_amdgcn_s_barrier();                                                \
    COMPUTE(bufb, ac);                                                           \
    __builtin_amdgcn_s_barrier();                                                \
  }

  f32x4 a0[4], a1[4];
  STAGE(0, 0);
  AML(a0, 0);
  for (int tp = 0; tp < 8; ++tp) {       // tiles 0..15
    STEP(0, a0, a1, 2 * tp);
    STEP(1, a1, a0, 2 * tp + 1);
  }
  // tile 16 (last): everything already staged into buf0, amask in a0
  asm volatile("s_waitcnt vmcnt(0)" ::: "memory");
  __builtin_amdgcn_s_barrier();
  COMPUTE(0, a0);
#undef STAGE
#undef AML
#undef COMPUTE
#undef STEP

  // deferred l reduction: combine the 4 lanes holding row lq
  lpart += __shfl_xor(lpart, 16);
  lpart += __shfl_xor(lpart, 32);

#pragma unroll
  for (int r = 0; r < 4; ++r) {
    int n = qbase + 4 * lg + r;
    float lr = __shfl(lpart, 4 * lg + r);
    float linv = (lr > 0.f) ? 1.f / lr : 0.f;
    size_t mrow = (size_t)b * NP + n;
#pragma unroll
    for (int j = 0; j < 4; ++j)
      O[mrow * D_ + h * HD + j * 16 + lq] = f2bf(oacc[j][r] * linv);
  }
}

// ---------------- K5: proj GEMM + bias -> fp32 (padded M), 2-phase dbuf ----------------
__global__ __launch_bounds__(256) void k_proj(const u16* __restrict__ ob, const u16* __restrict__ wtp,
                                              const float* __restrict__ bias, float* __restrict__ oproj) {
  __shared__ u16 sA[2][128 * 64];
  __shared__ u16 sB[2][128 * 64];
  const int m0 = blockIdx.y * 128;
  const int n0 = blockIdx.x * 128;
  const int t = threadIdx.x;
  const int wave = t >> 6, lane = t & 63;
  const int wm = wave >> 1, wn = wave & 1;
  const int lq = lane & 15, lg = lane >> 4;

  const int srow = lane >> 3;
  const int schunk = (lane & 7) ^ srow;

  f32x4 acc[4][4] = {};

#define PSTAGE(buf, k0_)                                                          \
  {                                                                               \
    _Pragma("unroll")                                                             \
    for (int p = 0; p < 4; ++p) {                                                 \
      int row = p * 32 + wave * 8 + srow;                                         \
      gload16(ob + (size_t)(m0 + row) * 512 + (k0_) + schunk * 8,                 \
              &sA[buf][p * 2048 + wave * 512 + lane * 8]);                        \
      gload16(wtp + (size_t)(n0 + row) * 512 + (k0_) + schunk * 8,                \
              &sB[buf][p * 2048 + wave * 512 + lane * 8]);                        \
    }                                                                             \
  }

  PSTAGE(0, 0);
  __syncthreads();
  int cur = 0;
  for (int k0 = 0; k0 < 512; k0 += 64) {
    if (k0 < 448) PSTAGE(cur ^ 1, k0 + 64);
#pragma unroll
    for (int kk = 0; kk < 2; ++kk) {
      bf16x8 af[4], bff[4];
      const int pc = (kk * 4 + lg) ^ (lq & 7);
#pragma unroll
      for (int f = 0; f < 4; ++f) {
        af[f]  = *reinterpret_cast<const bf16x8*>(&sA[cur][(wm * 64 + f * 16 + lq) * 64 + pc * 8]);
        bff[f] = *reinterpret_cast<const bf16x8*>(&sB[cur][(wn * 64 + f * 16 + lq) * 64 + pc * 8]);
      }
#pragma unroll
      for (int i = 0; i < 4; ++i)
#pragma unroll
        for (int j = 0; j < 4; ++j)
          acc[i][j] = __builtin_amdgcn_mfma_f32_16x16x32_bf16(af[i], bff[j], acc[i][j], 0, 0, 0);
    }
    __syncthreads();
    cur ^= 1;
  }
#undef PSTAGE

#pragma unroll
  for (int j = 0; j < 4; ++j) {
    int c = n0 + wn * 64 + j * 16 + lq;
    float bv = bias[c];
#pragma unroll
    for (int i = 0; i < 4; ++i) {
      int mbase = m0 + wm * 64 + i * 16 + lg * 4;
#pragma unroll
      for (int r = 0; r < 4; ++r) {
        int m = mbase + r;
        oproj[(size_t)m * D_ + c] = acc[i][j][r] + bv;
      }
    }
  }
}

// ---------------- K6: LN + residual (reads padded, writes real) ----------------
__global__ __launch_bounds__(256) void k_ln(const float* __restrict__ op, const float* __restrict__ gamma,
                                            const float* __restrict__ beta, float* __restrict__ out) {
  int row = blockIdx.x;
  int b = row / N_, n = row - b * N_;
  int t = threadIdx.x;
  const float* r = op + ((size_t)b * NP + n) * D_;
  float v0 = r[t], v1 = r[t + 256];
  float s = v0 + v1, sq = v0 * v0 + v1 * v1;
#pragma unroll
  for (int off = 1; off < 64; off <<= 1) { s += __shfl_xor(s, off); sq += __shfl_xor(sq, off); }
  __shared__ float ls[4], lsq[4];
  int wave = t >> 6, lane = t & 63;
  if (lane == 0) { ls[wave] = s; lsq[wave] = sq; }
  __syncthreads();
  float S = ls[0] + ls[1] + ls[2] + ls[3];
  float SQ = lsq[0] + lsq[1] + lsq[2] + lsq[3];
  float mu = S * (1.f / 512.f);
  float var = SQ * (1.f / 512.f) - mu * mu;
  float rinv = rsqrtf(var + 1e-5f);
  float g0 = gamma[t], g1 = gamma[t + 256], b0 = beta[t], b1 = beta[t + 256];
  out[(size_t)row * D_ + t]       = v0 + (v0 - mu) * rinv * g0 + b0;
  out[(size_t)row * D_ + t + 256] = v1 + (v1 - mu) * rinv * g1 + b1;
}

extern "C" void kernel_launch(void* const* d_in, const int* in_sizes, int n_in,
                              void* d_out, int out_size, void* d_ws, size_t ws_size,
                              hipStream_t stream) {
  const float* x     = (const float*)d_in[0];
  const float* wqkv  = (const float*)d_in[1];
  const float* wproj = (const float*)d_in[2];
  const float* bproj = (const float*)d_in[3];
  const float* gamma = (const float*)d_in[4];
  const float* beta  = (const float*)d_in[5];
  const float* mask  = (const float*)d_in[6];
  float* out = (float*)d_out;

  char* ws = (char*)d_ws;
  size_t off = 0;
  auto alloc = [&](size_t bytes) {
    void* p = ws + off;
    off = (off + bytes + 255) & ~(size_t)255;
    return p;
  };
  uint32_t* bmask = (uint32_t*)alloc((size_t)NP * WM * 4);
  float* am  = (float*)alloc((size_t)NQG * NTKV * 64 * 16 * 4);
  u16* wtq  = (u16*)alloc((size_t)3 * D_ * D_ * 2);
  u16* wtp  = (u16*)alloc((size_t)D_ * D_ * 2);
  u16* xb   = (u16*)alloc((size_t)MP * D_ * 2);
  u16* Qb   = (u16*)alloc((size_t)128 * NP * HD * 2);
  u16* Kb   = (u16*)alloc((size_t)128 * NP * HD * 2);
  u16* Vtb  = (u16*)alloc((size_t)128 * HD * NP * 2);
  u16* Ob   = (u16*)alloc((size_t)MP * D_ * 2);
  float* oproj = (float*)alloc((size_t)MP * D_ * 4);

  k_bitmask<<<dim3(NP), dim3(256), 0, stream>>>(mask, bmask);
  k_amask<<<dim3(NQG, NTKV), dim3(64), 0, stream>>>(bmask, am);
  k_wconv<<<dim3(3072), dim3(256), 0, stream>>>(wqkv, wproj, wtq, wtp);
  k_xconv<<<dim3(MP * D_ / (256 * 8)), dim3(256), 0, stream>>>(x, xb);
  k_qkv<<<dim3(12, MP / 128), dim3(256), 0, stream>>>(xb, wtq, Qb, Kb, Vtb);
  k_attn<<<dim3(9 * 128), dim3(512), 0, stream>>>(Qb, Kb, Vtb, am, Ob);
  k_proj<<<dim3(4, MP / 128), dim3(256), 0, stream>>>(Ob, wtp, bproj, oproj);
  k_ln<<<dim3(M_), dim3(256), 0, stream>>>(oproj, gamma, beta, out);
}